// Round 1
// baseline (4716.206 us; speedup 1.0000x reference)
//
#include <hip/hip_runtime.h>
#include <cstdint>
#include <cstddef>

#define NLV 12
#define NPL 10000
#define KE 3
#define EPL (NPL * KE)   // 30000 edges per level block
#define NE (11 * EPL)    // 330000
#define NT (NLV * NPL)   // 120000 nodes
#define H 100
#define H2 50
#define G3 300
#define FD 4
#define DM 30
#define NN 8             // nodes per wave

__device__ __forceinline__ float sigmoidf_(float x) {
    return 1.0f / (1.0f + __expf(-x));
}
__device__ __forceinline__ float tanhf_(float x) {
    // tanh(x) = 1 - 2/(e^{2x}+1); saturates correctly at +-inf
    float e = __expf(2.0f * x);
    return 1.0f - 2.0f / (e + 1.0f);
}

// ---------------------------------------------------------------------------
// Weight folding:  Wa = w2@pw1 (50x50), b2p = b2@pw1 (50),
//                  Wg = pw2@wh^T (50x300), bg = pb2@wh^T + bh (300)
// for both forward and backward parameter sets. 17850 outputs per direction.
// ---------------------------------------------------------------------------
__global__ void fold_kernel(
    const float* __restrict__ w2F, const float* __restrict__ b2F_,
    const float* __restrict__ pw1F, const float* __restrict__ pw2F,
    const float* __restrict__ pb2F, const float* __restrict__ whF,
    const float* __restrict__ bhF,
    const float* __restrict__ w2B, const float* __restrict__ b2B_,
    const float* __restrict__ pw1B, const float* __restrict__ pw2B,
    const float* __restrict__ pb2B, const float* __restrict__ whB,
    const float* __restrict__ bhB,
    float* __restrict__ WaF, float* __restrict__ b2pF,
    float* __restrict__ WgF, float* __restrict__ bgF,
    float* __restrict__ WaB, float* __restrict__ b2pB,
    float* __restrict__ WgB, float* __restrict__ bgB)
{
    int gid = blockIdx.x * blockDim.x + threadIdx.x;
    if (gid >= 2 * 17850) return;
    int dir = gid / 17850;
    int i = gid - dir * 17850;
    const float* w2  = dir ? w2B  : w2F;
    const float* b2  = dir ? b2B_ : b2F_;
    const float* pw1 = dir ? pw1B : pw1F;
    const float* pw2 = dir ? pw2B : pw2F;
    const float* pb2 = dir ? pb2B : pb2F;
    const float* wh  = dir ? whB  : whF;
    const float* bh  = dir ? bhB  : bhF;
    float* Wa  = dir ? WaB  : WaF;
    float* b2p = dir ? b2pB : b2pF;
    float* Wg  = dir ? WgB  : WgF;
    float* bg  = dir ? bgB  : bgF;

    if (i < 2500) {
        int r = i / 50, c = i - r * 50;
        float s = 0.f;
        for (int k = 0; k < 100; ++k) s += w2[r * 100 + k] * pw1[k * 50 + c];
        Wa[i] = s;
    } else if (i < 2550) {
        int c = i - 2500;
        float s = 0.f;
        for (int k = 0; k < 100; ++k) s += b2[k] * pw1[k * 50 + c];
        b2p[c] = s;
    } else if (i < 17550) {
        int j = i - 2550;
        int r = j / 300, g = j - r * 300;
        float s = 0.f;
        for (int k = 0; k < 100; ++k) s += pw2[r * 100 + k] * wh[g * 100 + k];
        Wg[j] = s;
    } else {
        int g = i - 17550;
        float s = bh[g];
        for (int k = 0; k < 100; ++k) s += pb2[k] * wh[g * 100 + k];
        bg[g] = s;
    }
}

// ---------------------------------------------------------------------------
// CSR build for backward aggregation (group edges of level-block f by src)
// ---------------------------------------------------------------------------
__global__ void csr_count(const int* __restrict__ src, int* __restrict__ counts)
{
    int e = blockIdx.x * blockDim.x + threadIdx.x;
    if (e >= NE) return;
    int f = e / EPL;
    int sl = src[e] - f * NPL;
    atomicAdd(&counts[f * NPL + sl], 1);
}

__global__ void csr_scan(const int* __restrict__ counts, int* __restrict__ offs)
{
    int f = blockIdx.x;           // one block per level 0..10
    int t = threadIdx.x;
    const int base = f * NPL;
    const int CH = 40;            // 256*40 = 10240 >= 10000
    __shared__ int part[256];
    int s = 0;
    for (int k = 0; k < CH; ++k) {
        int idx = t * CH + k;
        if (idx < NPL) s += counts[base + idx];
    }
    part[t] = s;
    __syncthreads();
    if (t == 0) {
        int run = 0;
        for (int j = 0; j < 256; ++j) { int tmp = part[j]; part[j] = run; run += tmp; }
    }
    __syncthreads();
    int run = part[t];
    for (int k = 0; k < CH; ++k) {
        int idx = t * CH + k;
        if (idx < NPL) { offs[base + idx] = run; run += counts[base + idx]; }
    }
}

__global__ void csr_fill(const int* __restrict__ src, const int* __restrict__ dst,
                         const int* __restrict__ offs, int* __restrict__ cursor,
                         int* __restrict__ nbrb)
{
    int e = blockIdx.x * blockDim.x + threadIdx.x;
    if (e >= NE) return;
    int f = e / EPL;
    int sl = src[e] - f * NPL;
    int p = atomicAdd(&cursor[f * NPL + sl], 1);
    nbrb[f * EPL + offs[f * NPL + sl] + p] = dst[e];
}

// ---------------------------------------------------------------------------
// xr = state @ proj_w + proj_b   (one wave per 8 nodes)
// ---------------------------------------------------------------------------
__global__ __launch_bounds__(64) void proj_kernel(
    const float* __restrict__ state, const float* __restrict__ pw,
    const float* __restrict__ pb, float* __restrict__ xr)
{
    int lane = threadIdx.x;
    long nb = (long)blockIdx.x * NN;
    __shared__ float A[NN][H];
    for (int n = 0; n < NN; ++n) {
        const float* rp = state + (nb + n) * H;
        if (lane < 50) { A[n][lane] = rp[lane]; A[n][lane + 50] = rp[lane + 50]; }
    }
    __syncthreads();
    if (lane < NN * FD) {
        int n = lane >> 2, f = lane & 3;
        float acc = pb[f];
        for (int i = 0; i < H; ++i) acc = fmaf(A[n][i], pw[i * FD + f], acc);
        xr[(nb + n) * FD + f] = acc;
    }
}

// ---------------------------------------------------------------------------
// Fused level step: edge-MLP(layer1)+agg -> folded node MLP -> GRU -> state
// One wave (64 threads) handles NN=8 nodes.
// ---------------------------------------------------------------------------
__global__ __launch_bounds__(64) void step_kernel(
    const float* __restrict__ state,        // full state (read rows of nbr ids)
    float* __restrict__ state_out,          // state + level*NPL*H
    const float* __restrict__ xr,           // xr slice for this level (NPL x 4)
    const int* __restrict__ nbr,            // per-edge neighbor global node id
    const int* __restrict__ offs,           // per-node start (NULL -> 3*j)
    const int* __restrict__ degs,           // per-node degree (NULL -> 3)
    const float* __restrict__ w1, const float* __restrict__ b1,       // (100x50),(50)
    const float* __restrict__ Wa, const float* __restrict__ b2p,      // (50x50),(50)
    const float* __restrict__ pb1,                                    // (50)
    const float* __restrict__ pw2, const float* __restrict__ pb2,     // (50x100),(100)
    const float* __restrict__ Wg, const float* __restrict__ bg,       // (50x300),(300)
    const float* __restrict__ wi, const float* __restrict__ bi)       // (300x4),(300)
{
    int lane = threadIdx.x;
    int nb = blockIdx.x * NN;   // local node base

    __shared__ float a50s[NN][H2];
    __shared__ float p50s[NN][H2];
    __shared__ float xrs[NN][FD];
    __shared__ int sdeg[NN], soff[NN];

    if (lane < NN) {
        int j = nb + lane;
        sdeg[lane] = degs ? degs[j] : KE;
        soff[lane] = offs ? offs[j] : KE * j;
    }
    if (lane < NN * FD) xrs[lane >> 2][lane & 3] = xr[nb * FD + lane];
    __syncthreads();

    int cc = (lane < H2) ? lane : 0;
    float b1c = b1[cc];

    int maxdeg = 0;
#pragma unroll
    for (int n = 0; n < NN; ++n) maxdeg = max(maxdeg, sdeg[n]);

    // ---- phase 1: a50[n][c] = sum_e relu(state[nbr_e] . w1[:,c] + b1[c]) ----
    float a50r[NN];
#pragma unroll
    for (int n = 0; n < NN; ++n) a50r[n] = 0.f;

    for (int s = 0; s < maxdeg; ++s) {
        const float* rp[NN];
#pragma unroll
        for (int n = 0; n < NN; ++n) {
            int row = 0;
            if (s < sdeg[n]) row = nbr[soff[n] + s];
            row = __builtin_amdgcn_readfirstlane(row);
            rp[n] = state + (size_t)row * H;
        }
        float acc[NN];
#pragma unroll
        for (int n = 0; n < NN; ++n) acc[n] = b1c;
        for (int i = 0; i < H; i += 4) {
            float wv0 = w1[(i + 0) * H2 + cc];
            float wv1 = w1[(i + 1) * H2 + cc];
            float wv2 = w1[(i + 2) * H2 + cc];
            float wv3 = w1[(i + 3) * H2 + cc];
#pragma unroll
            for (int n = 0; n < NN; ++n) {
                acc[n] = fmaf(rp[n][i + 0], wv0, acc[n]);
                acc[n] = fmaf(rp[n][i + 1], wv1, acc[n]);
                acc[n] = fmaf(rp[n][i + 2], wv2, acc[n]);
                acc[n] = fmaf(rp[n][i + 3], wv3, acc[n]);
            }
        }
#pragma unroll
        for (int n = 0; n < NN; ++n)
            if (s < sdeg[n]) a50r[n] += fmaxf(acc[n], 0.f);
    }
    if (lane < H2) {
#pragma unroll
        for (int n = 0; n < NN; ++n) a50s[n][lane] = a50r[n];
    }
    __syncthreads();

    // ---- phase 2: p50 = relu(a50 @ Wa + deg*b2p + pb1) ----
    float pacc[NN];
    {
        float bp = pb1[cc], bb = b2p[cc];
#pragma unroll
        for (int n = 0; n < NN; ++n) pacc[n] = bp + (float)sdeg[n] * bb;
        for (int i = 0; i < H2; ++i) {
            float w = Wa[i * H2 + cc];
#pragma unroll
            for (int n = 0; n < NN; ++n) pacc[n] = fmaf(a50s[n][i], w, pacc[n]);
        }
    }
    if (lane < H2) {
#pragma unroll
        for (int n = 0; n < NN; ++n) p50s[n][lane] = fmaxf(pacc[n], 0.f);
    }
    __syncthreads();

    // ---- phase 3: msg = p50@pw2+pb2 ; gh = p50@Wg+bg ; GRU ; write state ----
    for (int half = 0; half < 2; ++half) {
        int ch = lane + half * 64;
        if (ch < H) {
            float m[NN], gr[NN], gz[NN], gn[NN];
            float mb = pb2[ch], rb = bg[ch], zb = bg[ch + 100], nb2 = bg[ch + 200];
#pragma unroll
            for (int n = 0; n < NN; ++n) { m[n] = mb; gr[n] = rb; gz[n] = zb; gn[n] = nb2; }
            for (int i = 0; i < H2; ++i) {
                float wm = pw2[i * H + ch];
                float wr = Wg[i * G3 + ch];
                float wz = Wg[i * G3 + ch + 100];
                float wn = Wg[i * G3 + ch + 200];
#pragma unroll
                for (int n = 0; n < NN; ++n) {
                    float pv = p50s[n][i];
                    m[n]  = fmaf(pv, wm, m[n]);
                    gr[n] = fmaf(pv, wr, gr[n]);
                    gz[n] = fmaf(pv, wz, gz[n]);
                    gn[n] = fmaf(pv, wn, gn[n]);
                }
            }
            float wir0 = wi[ch * 4 + 0], wir1 = wi[ch * 4 + 1], wir2 = wi[ch * 4 + 2], wir3 = wi[ch * 4 + 3];
            float wiz0 = wi[(ch + 100) * 4 + 0], wiz1 = wi[(ch + 100) * 4 + 1], wiz2 = wi[(ch + 100) * 4 + 2], wiz3 = wi[(ch + 100) * 4 + 3];
            float win0 = wi[(ch + 200) * 4 + 0], win1 = wi[(ch + 200) * 4 + 1], win2 = wi[(ch + 200) * 4 + 2], win3 = wi[(ch + 200) * 4 + 3];
            float bir = bi[ch], biz = bi[ch + 100], bin = bi[ch + 200];
#pragma unroll
            for (int n = 0; n < NN; ++n) {
                float x0 = xrs[n][0], x1 = xrs[n][1], x2 = xrs[n][2], x3 = xrs[n][3];
                float gir = bir + x0 * wir0 + x1 * wir1 + x2 * wir2 + x3 * wir3;
                float giz = biz + x0 * wiz0 + x1 * wiz1 + x2 * wiz2 + x3 * wiz3;
                float gin = bin + x0 * win0 + x1 * win1 + x2 * win2 + x3 * win3;
                float r = sigmoidf_(gir + gr[n]);
                float z = sigmoidf_(giz + gz[n]);
                float t = tanhf_(gin + r * gn[n]);
                state_out[(size_t)(nb + n) * H + ch] = (1.f - z) * t + z * m[n];
            }
        }
    }
}

// ---------------------------------------------------------------------------
// Classification on level-0 nodes only (lit_mask kills everything else)
// ---------------------------------------------------------------------------
__global__ void cls_kernel(const float* __restrict__ state,
                           const float* __restrict__ w1, const float* __restrict__ b1,
                           const float* __restrict__ w2, const float* __restrict__ b2,
                           float* __restrict__ pred)
{
    int n = blockIdx.x * blockDim.x + threadIdx.x;
    if (n >= NPL) return;
    float h[DM];
#pragma unroll
    for (int j = 0; j < DM; ++j) h[j] = b1[j];
    const float* sp = state + (size_t)n * H;
    for (int i = 0; i < H; ++i) {
        float s = sp[i];
#pragma unroll
        for (int j = 0; j < DM; ++j) h[j] = fmaf(s, w1[i * DM + j], h[j]);
    }
    float v = b2[0];
#pragma unroll
    for (int j = 0; j < DM; ++j) v = fmaf(fmaxf(h[j], 0.f), w2[j], v);
    pred[n] = sigmoidf_(v);
}

// ---------------------------------------------------------------------------
// Hard gate evaluation, one level at a time (reads pred of level l-1)
// ---------------------------------------------------------------------------
__global__ void gate_kernel(const float* __restrict__ x, const int* __restrict__ src,
                            float* __restrict__ pred, int l)
{
    int j = blockIdx.x * blockDim.x + threadIdx.x;
    if (j >= NPL) return;
    int e0 = (l - 1) * EPL + KE * j;
    int dg = l * NPL + j;
    float v0 = pred[src[e0 + 0]];
    float v1 = pred[src[e0 + 1]];
    float v2 = pred[src[e0 + 2]];
    const float invT = 100.0f;   // 1 / HARD_T
    float mx = fmaxf(v0, fmaxf(v1, v2));
    float e0x = __expf((v0 - mx) * invT);
    float e1x = __expf((v1 - mx) * invT);
    float e2x = __expf((v2 - mx) * invT);
    float smax = (e0x * v0 + e1x * v1 + e2x * v2) / (e0x + e1x + e2x);
    float mn = fminf(v0, fminf(v1, v2));
    float f0 = __expf((mn - v0) * invT);
    float f1 = __expf((mn - v1) * invT);
    float f2 = __expf((mn - v2) * invT);
    float smin = (f0 * v0 + f1 * v1 + f2 * v2) / (f0 + f1 + f2);
    float am = x[(size_t)dg * FD + 1];
    float om = x[(size_t)dg * FD + 2];
    float nm = x[(size_t)dg * FD + 3];
    pred[dg] = am * smin + om * smax + nm * (3.f - (v0 + v1 + v2));
}

__global__ void copy_kernel(const float* __restrict__ pred, float* __restrict__ out)
{
    int j = blockIdx.x * blockDim.x + threadIdx.x;
    if (j < NPL) out[j] = pred[(NLV - 1) * NPL + j];
}

// ---------------------------------------------------------------------------
extern "C" void kernel_launch(void* const* d_in, const int* in_sizes, int n_in,
                              void* d_out, int out_size, void* d_ws, size_t ws_size,
                              hipStream_t stream)
{
    const float* x        = (const float*)d_in[0];
    const float* fpre_w1  = (const float*)d_in[1];
    const float* fpre_b1  = (const float*)d_in[2];
    const float* fpre_w2  = (const float*)d_in[3];
    const float* fpre_b2  = (const float*)d_in[4];
    const float* fpost_w1 = (const float*)d_in[5];
    const float* fpost_b1 = (const float*)d_in[6];
    const float* fpost_w2 = (const float*)d_in[7];
    const float* fpost_b2 = (const float*)d_in[8];
    const float* bpre_w1  = (const float*)d_in[9];
    const float* bpre_b1  = (const float*)d_in[10];
    const float* bpre_w2  = (const float*)d_in[11];
    const float* bpre_b2  = (const float*)d_in[12];
    const float* bpost_w1 = (const float*)d_in[13];
    const float* bpost_b1 = (const float*)d_in[14];
    const float* bpost_w2 = (const float*)d_in[15];
    const float* bpost_b2 = (const float*)d_in[16];
    const float* gruf_wi  = (const float*)d_in[17];
    const float* gruf_wh  = (const float*)d_in[18];
    const float* gruf_bi  = (const float*)d_in[19];
    const float* gruf_bh  = (const float*)d_in[20];
    const float* grub_wi  = (const float*)d_in[21];
    const float* grub_wh  = (const float*)d_in[22];
    const float* grub_bi  = (const float*)d_in[23];
    const float* grub_bh  = (const float*)d_in[24];
    const float* proj_w   = (const float*)d_in[25];
    const float* proj_b   = (const float*)d_in[26];
    const float* cls_w1   = (const float*)d_in[27];
    const float* cls_b1   = (const float*)d_in[28];
    const float* cls_w2   = (const float*)d_in[29];
    const float* cls_b2   = (const float*)d_in[30];
    const int*   src      = (const int*)d_in[31];
    const int*   dst      = (const int*)d_in[32];
    float* out = (float*)d_out;

    // ---- workspace carve ----
    size_t o = 0;
    auto carve = [&](size_t nbytes) -> void* {
        void* p = (char*)d_ws + o;
        o += (nbytes + 255) & ~(size_t)255;
        return p;
    };
    float* state = (float*)carve((size_t)NT * H * 4);      // 48 MB
    float* xr    = (float*)carve((size_t)NT * FD * 4);
    float* pred  = (float*)carve((size_t)NT * 4);
    float* WaF  = (float*)carve(2500 * 4);
    float* b2pF = (float*)carve(64 * 4);
    float* WgF  = (float*)carve(15000 * 4);
    float* bgF  = (float*)carve(320 * 4);
    float* WaB  = (float*)carve(2500 * 4);
    float* b2pB = (float*)carve(64 * 4);
    float* WgB  = (float*)carve(15000 * 4);
    float* bgB  = (float*)carve(320 * 4);
    int* counts = (int*)carve(11 * NPL * 4);
    int* offs   = (int*)carve(11 * NPL * 4);
    int* cursor = (int*)carve(11 * NPL * 4);
    int* nbrb   = (int*)carve((size_t)NE * 4);

    // ---- setup: zero state + CSR scratch, fold weights, build CSR ----
    hipMemsetAsync(state, 0, (size_t)NT * H * 4, stream);
    hipMemsetAsync(counts, 0, (char*)nbrb - (char*)counts, stream);

    fold_kernel<<<(2 * 17850 + 255) / 256, 256, 0, stream>>>(
        fpre_w2, fpre_b2, fpost_w1, fpost_w2, fpost_b2, gruf_wh, gruf_bh,
        bpre_w2, bpre_b2, bpost_w1, bpost_w2, bpost_b2, grub_wh, grub_bh,
        WaF, b2pF, WgF, bgF, WaB, b2pB, WgB, bgB);

    csr_count<<<(NE + 255) / 256, 256, 0, stream>>>(src, counts);
    csr_scan<<<11, 256, 0, stream>>>(counts, offs);
    csr_fill<<<(NE + 255) / 256, 256, 0, stream>>>(src, dst, offs, cursor, nbrb);

    const int stepGrid = NPL / NN;   // 1250

    for (int r = 0; r < 2; ++r) {
        const float* xr_use;
        if (r == 0) {
            xr_use = x;
        } else {
            proj_kernel<<<NT / NN, 64, 0, stream>>>(state, proj_w, proj_b, xr);
            xr_use = xr;
        }
        // forward levels 1..11
        for (int l = 1; l < NLV; ++l) {
            step_kernel<<<stepGrid, 64, 0, stream>>>(
                state, state + (size_t)l * NPL * H, xr_use + (size_t)l * NPL * FD,
                src + (size_t)(l - 1) * EPL, nullptr, nullptr,
                fpre_w1, fpre_b1, WaF, b2pF, fpost_b1,
                fpost_w2, fpost_b2, WgF, bgF, gruf_wi, gruf_bi);
        }
        // backward levels 10..0
        for (int f = NLV - 2; f >= 0; --f) {
            step_kernel<<<stepGrid, 64, 0, stream>>>(
                state, state + (size_t)f * NPL * H, xr_use + (size_t)f * NPL * FD,
                nbrb + (size_t)f * EPL, offs + (size_t)f * NPL, counts + (size_t)f * NPL,
                bpre_w1, bpre_b1, WaB, b2pB, bpost_b1,
                bpost_w2, bpost_b2, WgB, bgB, grub_wi, grub_bi);
        }
    }

    // ---- classification (level-0 only) + gate sweep ----
    cls_kernel<<<(NPL + 255) / 256, 256, 0, stream>>>(state, cls_w1, cls_b1, cls_w2, cls_b2, pred);
    for (int l = 1; l < NLV; ++l)
        gate_kernel<<<(NPL + 255) / 256, 256, 0, stream>>>(x, src, pred, l);
    copy_kernel<<<(NPL + 255) / 256, 256, 0, stream>>>(pred, out);
}

// Round 2
// 4398.354 us; speedup vs baseline: 1.0723x; 1.0723x over previous
//
#include <hip/hip_runtime.h>
#include <cstdint>
#include <cstddef>

#define NLV 12
#define NPL 10000
#define KE 3
#define EPL (NPL * KE)   // 30000 edges per level block
#define NE (11 * EPL)    // 330000
#define NT (NLV * NPL)   // 120000 nodes
#define H 100
#define H2 50
#define FD 4
#define DM 30
#define AP 52            // padded agg/p50 row stride (13 float4)

__device__ __forceinline__ float sigmoidf_(float x) {
    return 1.0f / (1.0f + __expf(-x));
}
__device__ __forceinline__ float tanhf_(float x) {
    float e = __expf(2.0f * x);
    return 1.0f - 2.0f / (e + 1.0f);
}

// ---------------------------------------------------------------------------
// Weight folding (per direction):
//   WaT[c*52+k]      = (w2@pw1)[k][c]                 (50x50, transposed+padded)
//   b2p[c]           = (b2@pw1)[c]
//   W4T[o*52+k], o<100:  pw2[k][o]        (msg weights)
//        o in [100,400): Wg[k][o-100] = sum_m pw2[k][m]*wh[o-100][m]
//   b4[o]: o<100: pb2[o]; else bh[g] + sum_m pb2[m]*wh[g][m]
// ---------------------------------------------------------------------------
__global__ void fold_kernel(
    const float* __restrict__ w2F, const float* __restrict__ b2F_,
    const float* __restrict__ pw1F, const float* __restrict__ pw2F,
    const float* __restrict__ pb2F, const float* __restrict__ whF,
    const float* __restrict__ bhF,
    const float* __restrict__ w2B, const float* __restrict__ b2B_,
    const float* __restrict__ pw1B, const float* __restrict__ pw2B,
    const float* __restrict__ pb2B, const float* __restrict__ whB,
    const float* __restrict__ bhB,
    float* __restrict__ WaTF, float* __restrict__ b2pF,
    float* __restrict__ W4TF, float* __restrict__ b4F,
    float* __restrict__ WaTB, float* __restrict__ b2pB,
    float* __restrict__ W4TB, float* __restrict__ b4B)
{
    int gid = blockIdx.x * blockDim.x + threadIdx.x;
    const int PER = 22950;
    if (gid >= 2 * PER) return;
    int dir = gid / PER;
    int i = gid - dir * PER;
    const float* w2  = dir ? w2B  : w2F;
    const float* b2  = dir ? b2B_ : b2F_;
    const float* pw1 = dir ? pw1B : pw1F;
    const float* pw2 = dir ? pw2B : pw2F;
    const float* pb2 = dir ? pb2B : pb2F;
    const float* wh  = dir ? whB  : whF;
    const float* bh  = dir ? bhB  : bhF;
    float* WaT = dir ? WaTB : WaTF;
    float* b2p = dir ? b2pB : b2pF;
    float* W4T = dir ? W4TB : W4TF;
    float* b4  = dir ? b4B  : b4F;

    if (i < 2500) {
        int c = i / 50, k = i - c * 50;
        float s = 0.f;
        for (int m = 0; m < 100; ++m) s += w2[k * 100 + m] * pw1[m * 50 + c];
        WaT[c * AP + k] = s;
    } else if (i < 2550) {
        int c = i - 2500;
        float s = 0.f;
        for (int m = 0; m < 100; ++m) s += b2[m] * pw1[m * 50 + c];
        b2p[c] = s;
    } else if (i < 22550) {
        int j = i - 2550;
        int o = j / 50, k = j - o * 50;
        if (o < 100) {
            W4T[o * AP + k] = pw2[k * 100 + o];
        } else {
            int g = o - 100;
            float s = 0.f;
            for (int m = 0; m < 100; ++m) s += pw2[k * 100 + m] * wh[g * 100 + m];
            W4T[o * AP + k] = s;
        }
    } else {
        int o = i - 22550;
        if (o < 100) b4[o] = pb2[o];
        else {
            int g = o - 100;
            float s = bh[g];
            for (int m = 0; m < 100; ++m) s += pb2[m] * wh[g * 100 + m];
            b4[o] = s;
        }
    }
}

// per-node in-degree for each backward level block (bias term needs deg)
__global__ void csr_count(const int* __restrict__ src, int* __restrict__ counts)
{
    int e = blockIdx.x * blockDim.x + threadIdx.x;
    if (e >= NE) return;
    int f = e / EPL;
    int sl = src[e] - f * NPL;
    atomicAdd(&counts[f * NPL + sl], 1);
}

// ---------------------------------------------------------------------------
// K1 forward: thread = (node, 5-channel group). 3 contiguous edges, no atomics.
// agg[node][c] = sum_e relu(b1[c] + state[src_e] . w1[:,c])
// ---------------------------------------------------------------------------
__global__ __launch_bounds__(256) void k1_fwd(
    const float* __restrict__ state, const int* __restrict__ nbr,
    const float* __restrict__ w1, const float* __restrict__ b1,
    float* __restrict__ agg)
{
    int gw = (blockIdx.x * 256 + threadIdx.x) >> 6;
    int lane = threadIdx.x & 63;
    int chg = __builtin_amdgcn_readfirstlane(gw % 10);
    int nw = gw / 10;
    int node = nw * 64 + lane;
    bool valid = node < NPL;
    int nd = valid ? node : 0;
    int c0 = chg * 5;

    const float4* rp0 = (const float4*)(state + (size_t)nbr[3 * nd + 0] * H);
    const float4* rp1 = (const float4*)(state + (size_t)nbr[3 * nd + 1] * H);
    const float4* rp2 = (const float4*)(state + (size_t)nbr[3 * nd + 2] * H);

    float e0[5], e1[5], e2[5];
#pragma unroll
    for (int j = 0; j < 5; ++j) { float b = b1[c0 + j]; e0[j] = b; e1[j] = b; e2[j] = b; }

    for (int i4 = 0; i4 < 25; ++i4) {
        float4 r0 = rp0[i4], r1 = rp1[i4], r2 = rp2[i4];
#pragma unroll
        for (int j = 0; j < 5; ++j) {
            float wa = w1[(4 * i4 + 0) * H2 + c0 + j];
            float wb = w1[(4 * i4 + 1) * H2 + c0 + j];
            float wc = w1[(4 * i4 + 2) * H2 + c0 + j];
            float wd = w1[(4 * i4 + 3) * H2 + c0 + j];
            e0[j] = fmaf(r0.x, wa, e0[j]); e0[j] = fmaf(r0.y, wb, e0[j]);
            e0[j] = fmaf(r0.z, wc, e0[j]); e0[j] = fmaf(r0.w, wd, e0[j]);
            e1[j] = fmaf(r1.x, wa, e1[j]); e1[j] = fmaf(r1.y, wb, e1[j]);
            e1[j] = fmaf(r1.z, wc, e1[j]); e1[j] = fmaf(r1.w, wd, e1[j]);
            e2[j] = fmaf(r2.x, wa, e2[j]); e2[j] = fmaf(r2.y, wb, e2[j]);
            e2[j] = fmaf(r2.z, wc, e2[j]); e2[j] = fmaf(r2.w, wd, e2[j]);
        }
    }
    if (valid) {
#pragma unroll
        for (int j = 0; j < 5; ++j)
            agg[(size_t)nd * AP + c0 + j] =
                fmaxf(e0[j], 0.f) + fmaxf(e1[j], 0.f) + fmaxf(e2[j], 0.f);
    }
}

// ---------------------------------------------------------------------------
// K1 backward: thread = (edge, 5-channel group); scatter with atomicAdd.
// agg[src_e - base][c] += relu(b1[c] + state[dst_e] . w1[:,c])
// ---------------------------------------------------------------------------
__global__ __launch_bounds__(256) void k1_bwd(
    const float* __restrict__ state, const int* __restrict__ nbr,
    const int* __restrict__ tgt, int tgtbase,
    const float* __restrict__ w1, const float* __restrict__ b1,
    float* __restrict__ agg)
{
    int gw = (blockIdx.x * 256 + threadIdx.x) >> 6;
    int lane = threadIdx.x & 63;
    int chg = __builtin_amdgcn_readfirstlane(gw % 10);
    int ew = gw / 10;
    int edge = ew * 64 + lane;
    bool valid = edge < EPL;
    int ed = valid ? edge : 0;
    int c0 = chg * 5;

    const float4* rp = (const float4*)(state + (size_t)nbr[ed] * H);
    int tl = tgt[ed] - tgtbase;

    float acc[5];
#pragma unroll
    for (int j = 0; j < 5; ++j) acc[j] = b1[c0 + j];

    for (int i4 = 0; i4 < 25; ++i4) {
        float4 rv = rp[i4];
#pragma unroll
        for (int j = 0; j < 5; ++j) {
            float wa = w1[(4 * i4 + 0) * H2 + c0 + j];
            float wb = w1[(4 * i4 + 1) * H2 + c0 + j];
            float wc = w1[(4 * i4 + 2) * H2 + c0 + j];
            float wd = w1[(4 * i4 + 3) * H2 + c0 + j];
            acc[j] = fmaf(rv.x, wa, acc[j]); acc[j] = fmaf(rv.y, wb, acc[j]);
            acc[j] = fmaf(rv.z, wc, acc[j]); acc[j] = fmaf(rv.w, wd, acc[j]);
        }
    }
    if (valid) {
#pragma unroll
        for (int j = 0; j < 5; ++j)
            atomicAdd(&agg[(size_t)tl * AP + c0 + j], fmaxf(acc[j], 0.f));
    }
}

// ---------------------------------------------------------------------------
// K2: folded post-MLP + GRU. 512 threads = 8 waves own 64 nodes (lane=node).
// Wave-uniform weights via s_load; per-lane rows in registers; coalesced
// state write via LDS round-trip. Also zeroes agg for the next step.
// ---------------------------------------------------------------------------
__global__ __launch_bounds__(512) void k2_kernel(
    const float* __restrict__ agg, const int* __restrict__ deg,
    const float* __restrict__ xrL,
    const float* __restrict__ WaT, const float* __restrict__ b2p,
    const float* __restrict__ pb1,
    const float* __restrict__ W4T, const float* __restrict__ b4,
    const float* __restrict__ wi, const float* __restrict__ bi,
    float* __restrict__ state_out, float* __restrict__ aggz)
{
    __shared__ float p50s[64 * AP];
    __shared__ float hs[64 * 101];
    int tid = threadIdx.x;
    int w = __builtin_amdgcn_readfirstlane(tid >> 6);
    int lane = tid & 63;
    int nb = blockIdx.x * 64;
    int node = nb + lane;
    bool valid = node < NPL;
    int nd = valid ? node : 0;

    // agg row -> registers
    float ar[AP];
    {
        const float4* ap = (const float4*)(agg + (size_t)nd * AP);
#pragma unroll
        for (int q = 0; q < 13; ++q) {
            float4 v = ap[q];
            ar[4 * q] = v.x; ar[4 * q + 1] = v.y; ar[4 * q + 2] = v.z; ar[4 * q + 3] = v.w;
        }
    }
    float dg = deg ? (float)deg[nd] : 3.0f;

    // phase B: wave w computes p50 cols [(50w)/8, (50(w+1))/8)
    int cA = (50 * w) >> 3, cB = (50 * (w + 1)) >> 3;
    for (int c = cA; c < cB; ++c) {
        float p = pb1[c] + dg * b2p[c];
        const float* wt = WaT + c * AP;
        for (int k = 0; k < 50; ++k) p = fmaf(ar[k], wt[k], p);
        p50s[lane * AP + c] = fmaxf(p, 0.f);
    }
    __syncthreads();

    // zero agg rows of this block's nodes (for next step's atomics)
    for (int idx = tid; idx < 64 * AP; idx += 512) {
        int n2 = nb + idx / AP;
        if (n2 < NPL) aggz[(size_t)n2 * AP + idx % AP] = 0.f;
    }

    // phase C: own p50 row -> registers
    float pr[AP];
    {
        const float4* pp = (const float4*)&p50s[lane * AP];
#pragma unroll
        for (int q = 0; q < 13; ++q) {
            float4 v = pp[q];
            pr[4 * q] = v.x; pr[4 * q + 1] = v.y; pr[4 * q + 2] = v.z; pr[4 * q + 3] = v.w;
        }
    }
    float x0, x1, x2, x3;
    {
        const float4* xp = (const float4*)(xrL + (size_t)nd * FD);
        float4 xv = *xp;
        x0 = xv.x; x1 = xv.y; x2 = xv.z; x3 = xv.w;
    }

    int oA = (100 * w) >> 3, oB = (100 * (w + 1)) >> 3;
    for (int o = oA; o < oB; ++o) {
        const float* wm = W4T + (size_t)o * AP;
        const float* wr = W4T + (size_t)(o + 100) * AP;
        const float* wz = W4T + (size_t)(o + 200) * AP;
        const float* wn = W4T + (size_t)(o + 300) * AP;
        float am = b4[o], arr = b4[o + 100], az = b4[o + 200], an = b4[o + 300];
        for (int k = 0; k < 50; ++k) {
            float pv = pr[k];
            am  = fmaf(pv, wm[k], am);
            arr = fmaf(pv, wr[k], arr);
            az  = fmaf(pv, wz[k], az);
            an  = fmaf(pv, wn[k], an);
        }
        float gir = bi[o]       + x0 * wi[o * 4 + 0]         + x1 * wi[o * 4 + 1]
                                + x2 * wi[o * 4 + 2]         + x3 * wi[o * 4 + 3];
        float giz = bi[o + 100] + x0 * wi[(o + 100) * 4 + 0] + x1 * wi[(o + 100) * 4 + 1]
                                + x2 * wi[(o + 100) * 4 + 2] + x3 * wi[(o + 100) * 4 + 3];
        float gin = bi[o + 200] + x0 * wi[(o + 200) * 4 + 0] + x1 * wi[(o + 200) * 4 + 1]
                                + x2 * wi[(o + 200) * 4 + 2] + x3 * wi[(o + 200) * 4 + 3];
        float r = sigmoidf_(gir + arr);
        float z = sigmoidf_(giz + az);
        float t = tanhf_(gin + r * an);
        hs[lane * 101 + o] = fmaf(z, am - t, t);   // (1-z)t + z*m
    }
    __syncthreads();

    int nvalid = min(64, NPL - nb);
    for (int idx = tid; idx < nvalid * 100; idx += 512) {
        int n2 = idx / 100, c = idx - n2 * 100;
        state_out[(size_t)(nb + n2) * H + c] = hs[n2 * 101 + c];
    }
}

// ---------------------------------------------------------------------------
// xr = state @ proj_w + proj_b ; thread = (node, f)
// ---------------------------------------------------------------------------
__global__ __launch_bounds__(256) void proj_kernel(
    const float* __restrict__ state, const float* __restrict__ pw,
    const float* __restrict__ pb, float* __restrict__ xr)
{
    int t = blockIdx.x * 256 + threadIdx.x;
    if (t >= NT * FD) return;
    int node = t >> 2, f = t & 3;
    const float4* rp = (const float4*)(state + (size_t)node * H);
    float acc = pb[f];
    for (int i4 = 0; i4 < 25; ++i4) {
        float4 v = rp[i4];
        acc = fmaf(v.x, pw[(4 * i4 + 0) * 4 + f], acc);
        acc = fmaf(v.y, pw[(4 * i4 + 1) * 4 + f], acc);
        acc = fmaf(v.z, pw[(4 * i4 + 2) * 4 + f], acc);
        acc = fmaf(v.w, pw[(4 * i4 + 3) * 4 + f], acc);
    }
    xr[t] = acc;
}

// ---------------------------------------------------------------------------
// Classification on level-0 nodes only
// ---------------------------------------------------------------------------
__global__ void cls_kernel(const float* __restrict__ state,
                           const float* __restrict__ w1, const float* __restrict__ b1,
                           const float* __restrict__ w2, const float* __restrict__ b2,
                           float* __restrict__ pred)
{
    int n = blockIdx.x * blockDim.x + threadIdx.x;
    if (n >= NPL) return;
    float h[DM];
#pragma unroll
    for (int j = 0; j < DM; ++j) h[j] = b1[j];
    const float* sp = state + (size_t)n * H;
    for (int i = 0; i < H; ++i) {
        float s = sp[i];
#pragma unroll
        for (int j = 0; j < DM; ++j) h[j] = fmaf(s, w1[i * DM + j], h[j]);
    }
    float v = b2[0];
#pragma unroll
    for (int j = 0; j < DM; ++j) v = fmaf(fmaxf(h[j], 0.f), w2[j], v);
    pred[n] = sigmoidf_(v);
}

// ---------------------------------------------------------------------------
// Hard gate evaluation, one level at a time
// ---------------------------------------------------------------------------
__global__ void gate_kernel(const float* __restrict__ x, const int* __restrict__ src,
                            float* __restrict__ pred, int l)
{
    int j = blockIdx.x * blockDim.x + threadIdx.x;
    if (j >= NPL) return;
    int e0 = (l - 1) * EPL + KE * j;
    int dg = l * NPL + j;
    float v0 = pred[src[e0 + 0]];
    float v1 = pred[src[e0 + 1]];
    float v2 = pred[src[e0 + 2]];
    const float invT = 100.0f;
    float mx = fmaxf(v0, fmaxf(v1, v2));
    float e0x = __expf((v0 - mx) * invT);
    float e1x = __expf((v1 - mx) * invT);
    float e2x = __expf((v2 - mx) * invT);
    float smax = (e0x * v0 + e1x * v1 + e2x * v2) / (e0x + e1x + e2x);
    float mn = fminf(v0, fminf(v1, v2));
    float f0 = __expf((mn - v0) * invT);
    float f1 = __expf((mn - v1) * invT);
    float f2 = __expf((mn - v2) * invT);
    float smin = (f0 * v0 + f1 * v1 + f2 * v2) / (f0 + f1 + f2);
    float am = x[(size_t)dg * FD + 1];
    float om = x[(size_t)dg * FD + 2];
    float nm = x[(size_t)dg * FD + 3];
    pred[dg] = am * smin + om * smax + nm * (3.f - (v0 + v1 + v2));
}

__global__ void copy_kernel(const float* __restrict__ pred, float* __restrict__ out)
{
    int j = blockIdx.x * blockDim.x + threadIdx.x;
    if (j < NPL) out[j] = pred[(NLV - 1) * NPL + j];
}

// ---------------------------------------------------------------------------
extern "C" void kernel_launch(void* const* d_in, const int* in_sizes, int n_in,
                              void* d_out, int out_size, void* d_ws, size_t ws_size,
                              hipStream_t stream)
{
    const float* x        = (const float*)d_in[0];
    const float* fpre_w1  = (const float*)d_in[1];
    const float* fpre_b1  = (const float*)d_in[2];
    const float* fpre_w2  = (const float*)d_in[3];
    const float* fpre_b2  = (const float*)d_in[4];
    const float* fpost_w1 = (const float*)d_in[5];
    const float* fpost_b1 = (const float*)d_in[6];
    const float* fpost_w2 = (const float*)d_in[7];
    const float* fpost_b2 = (const float*)d_in[8];
    const float* bpre_w1  = (const float*)d_in[9];
    const float* bpre_b1  = (const float*)d_in[10];
    const float* bpre_w2  = (const float*)d_in[11];
    const float* bpre_b2  = (const float*)d_in[12];
    const float* bpost_w1 = (const float*)d_in[13];
    const float* bpost_b1 = (const float*)d_in[14];
    const float* bpost_w2 = (const float*)d_in[15];
    const float* bpost_b2 = (const float*)d_in[16];
    const float* gruf_wi  = (const float*)d_in[17];
    const float* grub_wi  = (const float*)d_in[21];
    const float* gruf_wh  = (const float*)d_in[18];
    const float* gruf_bi  = (const float*)d_in[19];
    const float* gruf_bh  = (const float*)d_in[20];
    const float* grub_wh  = (const float*)d_in[22];
    const float* grub_bi  = (const float*)d_in[23];
    const float* grub_bh  = (const float*)d_in[24];
    const float* proj_w   = (const float*)d_in[25];
    const float* proj_b   = (const float*)d_in[26];
    const float* cls_w1   = (const float*)d_in[27];
    const float* cls_b1   = (const float*)d_in[28];
    const float* cls_w2   = (const float*)d_in[29];
    const float* cls_b2   = (const float*)d_in[30];
    const int*   src      = (const int*)d_in[31];
    const int*   dst      = (const int*)d_in[32];
    float* out = (float*)d_out;

    size_t o = 0;
    auto carve = [&](size_t nbytes) -> void* {
        void* p = (char*)d_ws + o;
        o += (nbytes + 255) & ~(size_t)255;
        return p;
    };
    float* state = (float*)carve((size_t)NT * H * 4);        // 48 MB
    float* xr    = (float*)carve((size_t)NT * FD * 4);
    float* pred  = (float*)carve((size_t)NT * 4);
    float* agg   = (float*)carve((size_t)NPL * AP * 4);      // 2.08 MB
    int*   counts= (int*)carve((size_t)11 * NPL * 4);
    float* WaTF  = (float*)carve(50 * AP * 4);
    float* b2pF  = (float*)carve(64 * 4);
    float* W4TF  = (float*)carve(400 * AP * 4);
    float* b4F   = (float*)carve(400 * 4);
    float* WaTB  = (float*)carve(50 * AP * 4);
    float* b2pB  = (float*)carve(64 * 4);
    float* W4TB  = (float*)carve(400 * AP * 4);
    float* b4B   = (float*)carve(400 * 4);

    // level-0 state must be zero (only slice read before written)
    hipMemsetAsync(state, 0, (size_t)NPL * H * 4, stream);
    hipMemsetAsync(counts, 0, (size_t)11 * NPL * 4, stream);

    fold_kernel<<<(2 * 22950 + 255) / 256, 256, 0, stream>>>(
        fpre_w2, fpre_b2, fpost_w1, fpost_w2, fpost_b2, gruf_wh, gruf_bh,
        bpre_w2, bpre_b2, bpost_w1, bpost_w2, bpost_b2, grub_wh, grub_bh,
        WaTF, b2pF, W4TF, b4F, WaTB, b2pB, W4TB, b4B);
    csr_count<<<(NE + 255) / 256, 256, 0, stream>>>(src, counts);

    const int k1fGrid = (10 * ((NPL + 63) / 64) * 64 + 255) / 256;  // 393
    const int k1bGrid = (10 * ((EPL + 63) / 64) * 64 + 255) / 256;  // 1173
    const int k2Grid  = (NPL + 63) / 64;                            // 157

    for (int r = 0; r < 2; ++r) {
        const float* xr_use;
        if (r == 0) {
            xr_use = x;
        } else {
            proj_kernel<<<(NT * FD + 255) / 256, 256, 0, stream>>>(state, proj_w, proj_b, xr);
            xr_use = xr;
        }
        for (int l = 1; l < NLV; ++l) {
            k1_fwd<<<k1fGrid, 256, 0, stream>>>(
                state, src + (size_t)(l - 1) * EPL, fpre_w1, fpre_b1, agg);
            k2_kernel<<<k2Grid, 512, 0, stream>>>(
                agg, nullptr, xr_use + (size_t)l * NPL * FD,
                WaTF, b2pF, fpost_b1, W4TF, b4F, gruf_wi, gruf_bi,
                state + (size_t)l * NPL * H, agg);
        }
        for (int f = NLV - 2; f >= 0; --f) {
            k1_bwd<<<k1bGrid, 256, 0, stream>>>(
                state, dst + (size_t)f * EPL, src + (size_t)f * EPL, f * NPL,
                bpre_w1, bpre_b1, agg);
            k2_kernel<<<k2Grid, 512, 0, stream>>>(
                agg, counts + (size_t)f * NPL, xr_use + (size_t)f * NPL * FD,
                WaTB, b2pB, bpost_b1, W4TB, b4B, grub_wi, grub_bi,
                state + (size_t)f * NPL * H, agg);
        }
    }

    cls_kernel<<<(NPL + 255) / 256, 256, 0, stream>>>(state, cls_w1, cls_b1, cls_w2, cls_b2, pred);
    for (int l = 1; l < NLV; ++l)
        gate_kernel<<<(NPL + 255) / 256, 256, 0, stream>>>(x, src, pred, l);
    copy_kernel<<<(NPL + 255) / 256, 256, 0, stream>>>(pred, out);
}

// Round 4
// 1970.847 us; speedup vs baseline: 2.3930x; 2.2317x over previous
//
#include <hip/hip_runtime.h>
#include <cstdint>
#include <cstddef>

#define NLV 12
#define NPL 10000
#define KE 3
#define EPL (NPL * KE)   // 30000 edges per level block
#define NE (11 * EPL)    // 330000
#define NT (NLV * NPL)   // 120000 nodes
#define H 100
#define H2 50
#define FD 4
#define DM 30
#define AP 52            // padded row stride (13 float4)

__device__ __forceinline__ float sigmoidf_(float x) {
    return 1.0f / (1.0f + __expf(-x));
}
__device__ __forceinline__ float tanhf_(float x) {
    float e = __expf(2.0f * x);
    return 1.0f - 2.0f / (e + 1.0f);
}

// ---------------------------------------------------------------------------
// Weight folding (per direction):
//   WaT[c*AP+k] = (w2@pw1)[k][c]   (50x50 T+pad)     b2p[c] = (b2@pw1)[c]
//   W4T[o*AP+k]: o<100 -> pw2[k][o] ; o in [100,400) -> sum_m pw2[k][m]*wh[o-100][m]
//   b4[o]: o<100 -> pb2[o] ; else bh[g] + sum_m pb2[m]*wh[g][m]
// ---------------------------------------------------------------------------
__global__ void fold_kernel(
    const float* __restrict__ w2F, const float* __restrict__ b2F_,
    const float* __restrict__ pw1F, const float* __restrict__ pw2F,
    const float* __restrict__ pb2F, const float* __restrict__ whF,
    const float* __restrict__ bhF,
    const float* __restrict__ w2B, const float* __restrict__ b2B_,
    const float* __restrict__ pw1B, const float* __restrict__ pw2B,
    const float* __restrict__ pb2B, const float* __restrict__ whB,
    const float* __restrict__ bhB,
    float* __restrict__ WaTF, float* __restrict__ b2pF,
    float* __restrict__ W4TF, float* __restrict__ b4F,
    float* __restrict__ WaTB, float* __restrict__ b2pB,
    float* __restrict__ W4TB, float* __restrict__ b4B)
{
    int gid = blockIdx.x * blockDim.x + threadIdx.x;
    const int PER = 22950;
    if (gid >= 2 * PER) return;
    int dir = gid / PER;
    int i = gid - dir * PER;
    const float* w2  = dir ? w2B  : w2F;
    const float* b2  = dir ? b2B_ : b2F_;
    const float* pw1 = dir ? pw1B : pw1F;
    const float* pw2 = dir ? pw2B : pw2F;
    const float* pb2 = dir ? pb2B : pb2F;
    const float* wh  = dir ? whB  : whF;
    const float* bh  = dir ? bhB  : bhF;
    float* WaT = dir ? WaTB : WaTF;
    float* b2p = dir ? b2pB : b2pF;
    float* W4T = dir ? W4TB : W4TF;
    float* b4  = dir ? b4B  : b4F;

    if (i < 2500) {
        int c = i / 50, k = i - c * 50;
        float s = 0.f;
        for (int m = 0; m < 100; ++m) s += w2[k * 100 + m] * pw1[m * 50 + c];
        WaT[c * AP + k] = s;
    } else if (i < 2550) {
        int c = i - 2500;
        float s = 0.f;
        for (int m = 0; m < 100; ++m) s += b2[m] * pw1[m * 50 + c];
        b2p[c] = s;
    } else if (i < 22550) {
        int j = i - 2550;
        int o = j / 50, k = j - o * 50;
        if (o < 100) {
            W4T[o * AP + k] = pw2[k * 100 + o];
        } else {
            int g = o - 100;
            float s = 0.f;
            for (int m = 0; m < 100; ++m) s += pw2[k * 100 + m] * wh[g * 100 + m];
            W4T[o * AP + k] = s;
        }
    } else {
        int o = i - 22550;
        if (o < 100) b4[o] = pb2[o];
        else {
            int g = o - 100;
            float s = bh[g];
            for (int m = 0; m < 100; ++m) s += pb2[m] * wh[g * 100 + m];
            b4[o] = s;
        }
    }
}

// ---------------------------------------------------------------------------
// CSR build (once): group level-f edges by src; store LOCAL dst index
// (dst - (f+1)*NPL). counts doubles as per-node degree for the bias term.
// ---------------------------------------------------------------------------
__global__ void csr_count(const int* __restrict__ src, int* __restrict__ counts)
{
    int e = blockIdx.x * blockDim.x + threadIdx.x;
    if (e >= NE) return;
    int f = e / EPL;
    int sl = src[e] - f * NPL;
    atomicAdd(&counts[f * NPL + sl], 1);
}

__global__ void csr_scan(const int* __restrict__ counts, int* __restrict__ offs)
{
    int f = blockIdx.x;           // one block per level 0..10
    int t = threadIdx.x;
    const int base = f * NPL;
    const int CH = 40;            // 256*40 >= 10000
    __shared__ int part[256];
    int s = 0;
    for (int k = 0; k < CH; ++k) {
        int idx = t * CH + k;
        if (idx < NPL) s += counts[base + idx];
    }
    part[t] = s;
    __syncthreads();
    if (t == 0) {
        int run = 0;
        for (int j = 0; j < 256; ++j) { int tmp = part[j]; part[j] = run; run += tmp; }
    }
    __syncthreads();
    int run = part[t];
    for (int k = 0; k < CH; ++k) {
        int idx = t * CH + k;
        if (idx < NPL) { offs[base + idx] = run; run += counts[base + idx]; }
    }
}

__global__ void csr_fill(const int* __restrict__ src, const int* __restrict__ dst,
                         const int* __restrict__ offs, int* __restrict__ cursor,
                         int* __restrict__ nbrb)
{
    int e = blockIdx.x * blockDim.x + threadIdx.x;
    if (e >= NE) return;
    int f = e / EPL;
    int sl = src[e] - f * NPL;
    int p = atomicAdd(&cursor[f * NPL + sl], 1);
    nbrb[f * EPL + offs[f * NPL + sl] + p] = dst[e] - (f + 1) * NPL;  // local id
}

// pre50 for level 0 with state = 0:  relu(b1[c]) broadcast; pads zero
__global__ void pre_init(const float* __restrict__ b1, float* __restrict__ preOut)
{
    int t = blockIdx.x * blockDim.x + threadIdx.x;
    if (t >= NPL * AP) return;
    int c = t % AP;
    preOut[t] = (c < H2) ? fmaxf(b1[c], 0.f) : 0.f;
}

// ---------------------------------------------------------------------------
// Fused level step. 512 threads = 8 waves own 64 nodes (lane = node).
//  A: agg[n] = sum over edges of pre50_in rows   (gather, no atomics)
//  B: p50 = relu(agg@WaT + deg*b2p + pb1)
//  C: folded 50x400 GEMM + GRU -> hs
//  E: coalesced state write
//  D: pre50_out[n] = relu(nb1 + hs[n]@nw1)   (next step's pre-MLP, from LDS)
// ---------------------------------------------------------------------------
__global__ __launch_bounds__(512) void k2_kernel(
    const float* __restrict__ preIn, float* __restrict__ preOut,
    const int* __restrict__ fedge, int srcbase,              // forward mode
    const int* __restrict__ boffs, const int* __restrict__ bdeg,
    const int* __restrict__ bnbr,                            // backward mode
    const float* __restrict__ xrL,
    const float* __restrict__ WaT, const float* __restrict__ b2p,
    const float* __restrict__ pb1,
    const float* __restrict__ W4T, const float* __restrict__ b4,
    const float* __restrict__ wi, const float* __restrict__ bi,
    const float* __restrict__ nw1, const float* __restrict__ nb1,
    float* __restrict__ state_out)
{
    __shared__ float smA[64 * AP];
    __shared__ float smP[64 * AP];
    __shared__ float hs[64 * 101];
    __shared__ int sed[192];
    __shared__ int soff[64];
    __shared__ int sdeg[64];

    int tid = threadIdx.x;
    int lane = tid & 63;
    int w = __builtin_amdgcn_readfirstlane(tid >> 6);
    int nb = blockIdx.x * 64;
    int node = nb + lane;
    bool valid = node < NPL;
    int nd = valid ? node : NPL - 1;

    // stage edge metadata
    if (fedge) {
        if (tid < 192) {
            int ei = nb * 3 + tid;
            sed[tid] = (ei < EPL) ? (fedge[ei] - srcbase) : 0;
        }
    } else {
        if (tid < 64) {
            int n2 = nb + tid;
            soff[tid] = (n2 < NPL) ? boffs[n2] : 0;
            sdeg[tid] = (n2 < NPL) ? bdeg[n2] : 0;
        }
    }
    __syncthreads();

    // ---- phase A: gather + sum pre50 rows ----
    const float4* pre4 = (const float4*)preIn;
    for (int idx = tid; idx < 64 * 13; idx += 512) {
        int n = idx / 13, q = idx - n * 13;
        float4 a = make_float4(0.f, 0.f, 0.f, 0.f);
        if (nb + n < NPL) {
            if (fedge) {
#pragma unroll
                for (int e = 0; e < 3; ++e) {
                    int r = sed[3 * n + e];
                    float4 v = pre4[r * 13 + q];
                    a.x += v.x; a.y += v.y; a.z += v.z; a.w += v.w;
                }
            } else {
                int off = soff[n], d = sdeg[n];
                for (int e = 0; e < d; ++e) {
                    int r = bnbr[off + e];
                    float4 v = pre4[r * 13 + q];
                    a.x += v.x; a.y += v.y; a.z += v.z; a.w += v.w;
                }
            }
        }
        *(float4*)&smA[n * AP + 4 * q] = a;
    }
    __syncthreads();

    // ---- phase B: p50 = relu(agg@WaT + deg*b2p + pb1) ----
    float ar[AP];
    {
        const float4* ap = (const float4*)&smA[lane * AP];
#pragma unroll
        for (int q = 0; q < 13; ++q) {
            float4 v = ap[q];
            ar[4 * q] = v.x; ar[4 * q + 1] = v.y; ar[4 * q + 2] = v.z; ar[4 * q + 3] = v.w;
        }
    }
    float dgv = fedge ? 3.0f : (float)sdeg[lane];
    int cA = (50 * w) >> 3, cB = (50 * (w + 1)) >> 3;
    for (int c = cA; c < cB; ++c) {
        float p = pb1[c] + dgv * b2p[c];
        const float* wt = WaT + c * AP;
        for (int k = 0; k < 50; ++k) p = fmaf(ar[k], wt[k], p);
        smP[lane * AP + c] = fmaxf(p, 0.f);
    }
    __syncthreads();

    // ---- phase C: folded GEMM + GRU ----
    float pr[AP];
    {
        const float4* pp = (const float4*)&smP[lane * AP];
#pragma unroll
        for (int q = 0; q < 13; ++q) {
            float4 v = pp[q];
            pr[4 * q] = v.x; pr[4 * q + 1] = v.y; pr[4 * q + 2] = v.z; pr[4 * q + 3] = v.w;
        }
    }
    float4 xv = ((const float4*)xrL)[nd];
    int oA = (100 * w) >> 3, oB = (100 * (w + 1)) >> 3;
    for (int o = oA; o < oB; ++o) {
        const float* wm = W4T + (size_t)o * AP;
        const float* wr = W4T + (size_t)(o + 100) * AP;
        const float* wz = W4T + (size_t)(o + 200) * AP;
        const float* wn = W4T + (size_t)(o + 300) * AP;
        float am = b4[o], arr = b4[o + 100], az = b4[o + 200], an = b4[o + 300];
        for (int k = 0; k < 50; ++k) {
            float pv = pr[k];
            am  = fmaf(pv, wm[k], am);
            arr = fmaf(pv, wr[k], arr);
            az  = fmaf(pv, wz[k], az);
            an  = fmaf(pv, wn[k], an);
        }
        float gir = bi[o]       + xv.x * wi[o * 4 + 0]         + xv.y * wi[o * 4 + 1]
                                + xv.z * wi[o * 4 + 2]         + xv.w * wi[o * 4 + 3];
        float giz = bi[o + 100] + xv.x * wi[(o + 100) * 4 + 0] + xv.y * wi[(o + 100) * 4 + 1]
                                + xv.z * wi[(o + 100) * 4 + 2] + xv.w * wi[(o + 100) * 4 + 3];
        float gin = bi[o + 200] + xv.x * wi[(o + 200) * 4 + 0] + xv.y * wi[(o + 200) * 4 + 1]
                                + xv.z * wi[(o + 200) * 4 + 2] + xv.w * wi[(o + 200) * 4 + 3];
        float r = sigmoidf_(gir + arr);
        float z = sigmoidf_(giz + az);
        float t = tanhf_(gin + r * an);
        hs[lane * 101 + o] = fmaf(z, am - t, t);   // (1-z)t + z*m
    }
    __syncthreads();

    // ---- phase E: coalesced state write ----
    int nvalid = min(64, NPL - nb);
    for (int idx = tid; idx < nvalid * 100; idx += 512) {
        int n2 = idx / 100, c = idx - n2 * 100;
        state_out[(size_t)(nb + n2) * H + c] = hs[n2 * 101 + c];
    }

    // ---- phase D: next step's pre50 from hs ----
    {
        int c0 = 7 * w;
        int cn = min(c0 + 7, 50) - c0;   // 7 (w<7) or 1 (w==7)
        if (cn > 0) {
            int cj[7];
#pragma unroll
            for (int j = 0; j < 7; ++j) cj[j] = (c0 + j < 50) ? (c0 + j) : 49;
            float acc[7];
#pragma unroll
            for (int j = 0; j < 7; ++j) acc[j] = nb1[cj[j]];
            for (int k = 0; k < 100; ++k) {
                float hv = hs[lane * 101 + k];
#pragma unroll
                for (int j = 0; j < 7; ++j)
                    acc[j] = fmaf(hv, nw1[k * 50 + cj[j]], acc[j]);
            }
            if (valid) {
                for (int j = 0; j < cn; ++j)
                    preOut[(size_t)node * AP + c0 + j] = fmaxf(acc[j], 0.f);
                if (w == 7) {
                    preOut[(size_t)node * AP + 50] = 0.f;
                    preOut[(size_t)node * AP + 51] = 0.f;
                }
            }
        }
    }
}

// ---------------------------------------------------------------------------
// xr = state @ proj_w + proj_b ; thread = (node, f)
// ---------------------------------------------------------------------------
__global__ __launch_bounds__(256) void proj_kernel(
    const float* __restrict__ state, const float* __restrict__ pw,
    const float* __restrict__ pb, float* __restrict__ xr)
{
    int t = blockIdx.x * 256 + threadIdx.x;
    if (t >= NT * FD) return;
    int node = t >> 2, f = t & 3;
    const float4* rp = (const float4*)(state + (size_t)node * H);
    float acc = pb[f];
    for (int i4 = 0; i4 < 25; ++i4) {
        float4 v = rp[i4];
        acc = fmaf(v.x, pw[(4 * i4 + 0) * 4 + f], acc);
        acc = fmaf(v.y, pw[(4 * i4 + 1) * 4 + f], acc);
        acc = fmaf(v.z, pw[(4 * i4 + 2) * 4 + f], acc);
        acc = fmaf(v.w, pw[(4 * i4 + 3) * 4 + f], acc);
    }
    xr[t] = acc;
}

// ---------------------------------------------------------------------------
// Classification on level-0 nodes only
// ---------------------------------------------------------------------------
__global__ void cls_kernel(const float* __restrict__ state,
                           const float* __restrict__ w1, const float* __restrict__ b1,
                           const float* __restrict__ w2, const float* __restrict__ b2,
                           float* __restrict__ pred)
{
    int n = blockIdx.x * blockDim.x + threadIdx.x;
    if (n >= NPL) return;
    float h[DM];
#pragma unroll
    for (int j = 0; j < DM; ++j) h[j] = b1[j];
    const float* sp = state + (size_t)n * H;
    for (int i = 0; i < H; ++i) {
        float s = sp[i];
#pragma unroll
        for (int j = 0; j < DM; ++j) h[j] = fmaf(s, w1[i * DM + j], h[j]);
    }
    float v = b2[0];
#pragma unroll
    for (int j = 0; j < DM; ++j) v = fmaf(fmaxf(h[j], 0.f), w2[j], v);
    pred[n] = sigmoidf_(v);
}

// ---------------------------------------------------------------------------
// Hard gate evaluation, one level at a time
// ---------------------------------------------------------------------------
__global__ void gate_kernel(const float* __restrict__ x, const int* __restrict__ src,
                            float* __restrict__ pred, int l)
{
    int j = blockIdx.x * blockDim.x + threadIdx.x;
    if (j >= NPL) return;
    int e0 = (l - 1) * EPL + KE * j;
    int dg = l * NPL + j;
    float v0 = pred[src[e0 + 0]];
    float v1 = pred[src[e0 + 1]];
    float v2 = pred[src[e0 + 2]];
    const float invT = 100.0f;
    float mx = fmaxf(v0, fmaxf(v1, v2));
    float e0x = __expf((v0 - mx) * invT);
    float e1x = __expf((v1 - mx) * invT);
    float e2x = __expf((v2 - mx) * invT);
    float smax = (e0x * v0 + e1x * v1 + e2x * v2) / (e0x + e1x + e2x);
    float mn = fminf(v0, fminf(v1, v2));
    float f0 = __expf((mn - v0) * invT);
    float f1 = __expf((mn - v1) * invT);
    float f2 = __expf((mn - v2) * invT);
    float smin = (f0 * v0 + f1 * v1 + f2 * v2) / (f0 + f1 + f2);
    float am = x[(size_t)dg * FD + 1];
    float om = x[(size_t)dg * FD + 2];
    float nm = x[(size_t)dg * FD + 3];
    pred[dg] = am * smin + om * smax + nm * (3.f - (v0 + v1 + v2));
}

__global__ void copy_kernel(const float* __restrict__ pred, float* __restrict__ out)
{
    int j = blockIdx.x * blockDim.x + threadIdx.x;
    if (j < NPL) out[j] = pred[(NLV - 1) * NPL + j];
}

// ---------------------------------------------------------------------------
extern "C" void kernel_launch(void* const* d_in, const int* in_sizes, int n_in,
                              void* d_out, int out_size, void* d_ws, size_t ws_size,
                              hipStream_t stream)
{
    const float* x        = (const float*)d_in[0];
    const float* fpre_w1  = (const float*)d_in[1];
    const float* fpre_b1  = (const float*)d_in[2];
    const float* fpre_w2  = (const float*)d_in[3];
    const float* fpre_b2  = (const float*)d_in[4];
    const float* fpost_w1 = (const float*)d_in[5];
    const float* fpost_b1 = (const float*)d_in[6];
    const float* fpost_w2 = (const float*)d_in[7];
    const float* fpost_b2 = (const float*)d_in[8];
    const float* bpre_w1  = (const float*)d_in[9];
    const float* bpre_b1  = (const float*)d_in[10];
    const float* bpre_w2  = (const float*)d_in[11];
    const float* bpre_b2  = (const float*)d_in[12];
    const float* bpost_w1 = (const float*)d_in[13];
    const float* bpost_b1 = (const float*)d_in[14];
    const float* bpost_w2 = (const float*)d_in[15];
    const float* bpost_b2 = (const float*)d_in[16];
    const float* gruf_wi  = (const float*)d_in[17];
    const float* gruf_wh  = (const float*)d_in[18];
    const float* gruf_bi  = (const float*)d_in[19];
    const float* gruf_bh  = (const float*)d_in[20];
    const float* grub_wi  = (const float*)d_in[21];
    const float* grub_wh  = (const float*)d_in[22];
    const float* grub_bi  = (const float*)d_in[23];
    const float* grub_bh  = (const float*)d_in[24];
    const float* proj_w   = (const float*)d_in[25];
    const float* proj_b   = (const float*)d_in[26];
    const float* cls_w1   = (const float*)d_in[27];
    const float* cls_b1   = (const float*)d_in[28];
    const float* cls_w2   = (const float*)d_in[29];
    const float* cls_b2   = (const float*)d_in[30];
    const int*   src      = (const int*)d_in[31];
    const int*   dst      = (const int*)d_in[32];
    float* out = (float*)d_out;

    size_t o = 0;
    auto carve = [&](size_t nbytes) -> void* {
        void* p = (char*)d_ws + o;
        o += (nbytes + 255) & ~(size_t)255;
        return p;
    };
    float* state = (float*)carve((size_t)NT * H * 4);        // 48 MB
    float* xr    = (float*)carve((size_t)NT * FD * 4);
    float* pred  = (float*)carve((size_t)NT * 4);
    float* pre0  = (float*)carve((size_t)NPL * AP * 4);      // 2.08 MB
    float* pre1  = (float*)carve((size_t)NPL * AP * 4);
    int*   counts= (int*)carve((size_t)11 * NPL * 4);
    int*   cursor= (int*)carve((size_t)11 * NPL * 4);
    int*   offs  = (int*)carve((size_t)11 * NPL * 4);
    int*   nbrb  = (int*)carve((size_t)NE * 4);
    float* WaTF  = (float*)carve(50 * AP * 4);
    float* b2pF  = (float*)carve(64 * 4);
    float* W4TF  = (float*)carve(400 * AP * 4);
    float* b4F   = (float*)carve(400 * 4);
    float* WaTB  = (float*)carve(50 * AP * 4);
    float* b2pB  = (float*)carve(64 * 4);
    float* W4TB  = (float*)carve(400 * AP * 4);
    float* b4B   = (float*)carve(400 * 4);

    // zero counts AND cursor — INCLUDING the 256-byte alignment padding
    // between them (round-3 bug: 22*NPL*4 missed cursor's tail 64 bytes
    // because counts is rounded up to 440064; poisoned cursor -> wild
    // nbrb writes -> memory fault).
    hipMemsetAsync(counts, 0, (size_t)((char*)offs - (char*)counts), stream);

    fold_kernel<<<(2 * 22950 + 255) / 256, 256, 0, stream>>>(
        fpre_w2, fpre_b2, fpost_w1, fpost_w2, fpost_b2, gruf_wh, gruf_bh,
        bpre_w2, bpre_b2, bpost_w1, bpost_w2, bpost_b2, grub_wh, grub_bh,
        WaTF, b2pF, W4TF, b4F, WaTB, b2pB, W4TB, b4B);
    csr_count<<<(NE + 255) / 256, 256, 0, stream>>>(src, counts);
    csr_scan<<<11, 256, 0, stream>>>(counts, offs);
    csr_fill<<<(NE + 255) / 256, 256, 0, stream>>>(src, dst, offs, cursor, nbrb);
    pre_init<<<(NPL * AP + 255) / 256, 256, 0, stream>>>(fpre_b1, pre0);

    float* preBuf[2] = { pre0, pre1 };
    int pb = 0;
    const int k2Grid = (NPL + 63) / 64;   // 157

    for (int r = 0; r < 2; ++r) {
        const float* xr_use;
        if (r == 0) {
            xr_use = x;
        } else {
            proj_kernel<<<(NT * FD + 255) / 256, 256, 0, stream>>>(state, proj_w, proj_b, xr);
            xr_use = xr;
        }
        // forward levels 1..11
        for (int l = 1; l < NLV; ++l) {
            bool lastf = (l == NLV - 1);
            k2_kernel<<<k2Grid, 512, 0, stream>>>(
                preBuf[pb], preBuf[pb ^ 1],
                src + (size_t)(l - 1) * EPL, (l - 1) * NPL,
                nullptr, nullptr, nullptr,
                xr_use + (size_t)l * NPL * FD,
                WaTF, b2pF, fpost_b1, W4TF, b4F, gruf_wi, gruf_bi,
                lastf ? bpre_w1 : fpre_w1, lastf ? bpre_b1 : fpre_b1,
                state + (size_t)l * NPL * H);
            pb ^= 1;
        }
        // backward levels 10..0
        for (int f = NLV - 2; f >= 0; --f) {
            bool lastb = (f == 0);
            k2_kernel<<<k2Grid, 512, 0, stream>>>(
                preBuf[pb], preBuf[pb ^ 1],
                nullptr, 0,
                offs + (size_t)f * NPL, counts + (size_t)f * NPL, nbrb + (size_t)f * EPL,
                xr_use + (size_t)f * NPL * FD,
                WaTB, b2pB, bpost_b1, W4TB, b4B, grub_wi, grub_bi,
                lastb ? fpre_w1 : bpre_w1, lastb ? fpre_b1 : bpre_b1,
                state + (size_t)f * NPL * H);
            pb ^= 1;
        }
    }

    cls_kernel<<<(NPL + 255) / 256, 256, 0, stream>>>(state, cls_w1, cls_b1, cls_w2, cls_b2, pred);
    for (int l = 1; l < NLV; ++l)
        gate_kernel<<<(NPL + 255) / 256, 256, 0, stream>>>(x, src, pred, l);
    copy_kernel<<<(NPL + 255) / 256, 256, 0, stream>>>(pred, out);
}

// Round 5
// 592.603 us; speedup vs baseline: 7.9585x; 3.3257x over previous
//
#include <hip/hip_runtime.h>
#include <cstdint>
#include <cstddef>

#define NLV 12
#define NPL 10000
#define KE 3
#define EPL (NPL * KE)   // 30000 edges per level block
#define NE (11 * EPL)    // 330000
#define NT (NLV * NPL)   // 120000 nodes
#define H 100
#define H2 50
#define FD 4
#define DM 30
#define AP 52            // pre50 row stride (13 float4)
#define TN 40            // nodes per block (250 blocks exactly)
#define YS 404           // Y LDS row stride (dwords)
#define HSS 104          // hs LDS row stride
#define NWS 108          // nwT row stride

__device__ __forceinline__ float sigmoidf_(float x) {
    return 1.0f / (1.0f + __expf(-x));
}
__device__ __forceinline__ float tanhf_(float x) {
    float e = __expf(2.0f * x);
    return 1.0f - 2.0f / (e + 1.0f);
}

// ---------------------------------------------------------------------------
// Weight folding per direction (PER = 28350 outputs):
//  WaT[c*52+k]   = (w2@pw1)[k][c]                        (i < 2500)
//  b2p[c]        = (b2@pw1)[c]                           (2500..2550)
//  W4i[k*400+c]  c=4o+g: g0: pw2[k][o]                   (2550..22550)
//                g1..3: sum_m pw2[k][m]*wh[(g-1)*100+o][m]
//  b4i[c]        g0: pb2[o]; g1: bh[o]+fold+bi[o];       (22550..22950)
//                g2: bh[100+o]+fold+bi[100+o]; g3: bh[200+o]+fold
//  nwT[c*108+k]  = (k<100) ? w1pre[k*50+c] : 0           (22950..28350)
// ---------------------------------------------------------------------------
__global__ void fold_kernel(
    const float* __restrict__ w2F, const float* __restrict__ b2F_,
    const float* __restrict__ pw1F, const float* __restrict__ pw2F,
    const float* __restrict__ pb2F, const float* __restrict__ whF,
    const float* __restrict__ bhF, const float* __restrict__ biF,
    const float* __restrict__ w1pF,
    const float* __restrict__ w2B, const float* __restrict__ b2B_,
    const float* __restrict__ pw1B, const float* __restrict__ pw2B,
    const float* __restrict__ pb2B, const float* __restrict__ whB,
    const float* __restrict__ bhB, const float* __restrict__ biB,
    const float* __restrict__ w1pB,
    float* __restrict__ WaTF, float* __restrict__ b2pF,
    float* __restrict__ W4iF, float* __restrict__ b4iF, float* __restrict__ nwTF,
    float* __restrict__ WaTB, float* __restrict__ b2pB,
    float* __restrict__ W4iB, float* __restrict__ b4iB, float* __restrict__ nwTB)
{
    const int PER = 28350;
    int gid = blockIdx.x * blockDim.x + threadIdx.x;
    if (gid >= 2 * PER) return;
    int dir = gid / PER;
    int i = gid - dir * PER;
    const float* w2  = dir ? w2B  : w2F;
    const float* b2  = dir ? b2B_ : b2F_;
    const float* pw1 = dir ? pw1B : pw1F;
    const float* pw2 = dir ? pw2B : pw2F;
    const float* pb2 = dir ? pb2B : pb2F;
    const float* wh  = dir ? whB  : whF;
    const float* bh  = dir ? bhB  : bhF;
    const float* bi  = dir ? biB  : biF;
    const float* w1p = dir ? w1pB : w1pF;
    float* WaT = dir ? WaTB : WaTF;
    float* b2p = dir ? b2pB : b2pF;
    float* W4i = dir ? W4iB : W4iF;
    float* b4i = dir ? b4iB : b4iF;
    float* nwT = dir ? nwTB : nwTF;

    if (i < 2500) {
        int c = i / 50, k = i - c * 50;
        float s = 0.f;
        for (int m = 0; m < 100; ++m) s += w2[k * 100 + m] * pw1[m * 50 + c];
        WaT[c * AP + k] = s;
    } else if (i < 2550) {
        int c = i - 2500;
        float s = 0.f;
        for (int m = 0; m < 100; ++m) s += b2[m] * pw1[m * 50 + c];
        b2p[c] = s;
    } else if (i < 22550) {
        int j = i - 2550;
        int k = j / 400, c = j - k * 400;
        int o = c >> 2, g = c & 3;
        float s;
        if (g == 0) {
            s = pw2[k * 100 + o];
        } else {
            int row = (g - 1) * 100 + o;
            s = 0.f;
            for (int m = 0; m < 100; ++m) s += pw2[k * 100 + m] * wh[row * 100 + m];
        }
        W4i[k * 400 + c] = s;
    } else if (i < 22950) {
        int c = i - 22550;
        int o = c >> 2, g = c & 3;
        float s;
        if (g == 0) {
            s = pb2[o];
        } else {
            int row = (g - 1) * 100 + o;
            s = bh[row];
            for (int m = 0; m < 100; ++m) s += pb2[m] * wh[row * 100 + m];
            if (g == 1) s += bi[o];
            else if (g == 2) s += bi[100 + o];
        }
        b4i[c] = s;
    } else {
        int j = i - 22950;
        int c = j / NWS, k = j - c * NWS;
        nwT[c * NWS + k] = (k < 100) ? w1p[k * 50 + c] : 0.f;
    }
}

// ---------------------------------------------------------------------------
// CSR build (once): group level-f edges by src; store LOCAL dst index.
// counts doubles as per-node in-degree.
// ---------------------------------------------------------------------------
__global__ void csr_count(const int* __restrict__ src, int* __restrict__ counts)
{
    int e = blockIdx.x * blockDim.x + threadIdx.x;
    if (e >= NE) return;
    int f = e / EPL;
    int sl = src[e] - f * NPL;
    atomicAdd(&counts[f * NPL + sl], 1);
}

__global__ void csr_scan(const int* __restrict__ counts, int* __restrict__ offs)
{
    int f = blockIdx.x;
    int t = threadIdx.x;
    const int base = f * NPL;
    const int CH = 40;
    __shared__ int part[256];
    int s = 0;
    for (int k = 0; k < CH; ++k) {
        int idx = t * CH + k;
        if (idx < NPL) s += counts[base + idx];
    }
    part[t] = s;
    __syncthreads();
    if (t == 0) {
        int run = 0;
        for (int j = 0; j < 256; ++j) { int tmp = part[j]; part[j] = run; run += tmp; }
    }
    __syncthreads();
    int run = part[t];
    for (int k = 0; k < CH; ++k) {
        int idx = t * CH + k;
        if (idx < NPL) { offs[base + idx] = run; run += counts[base + idx]; }
    }
}

__global__ void csr_fill(const int* __restrict__ src, const int* __restrict__ dst,
                         const int* __restrict__ offs, int* __restrict__ cursor,
                         int* __restrict__ nbrb)
{
    int e = blockIdx.x * blockDim.x + threadIdx.x;
    if (e >= NE) return;
    int f = e / EPL;
    int sl = src[e] - f * NPL;
    int p = atomicAdd(&cursor[f * NPL + sl], 1);
    nbrb[f * EPL + offs[f * NPL + sl] + p] = dst[e] - (f + 1) * NPL;
}

// pre0 = relu(b1) broadcast (+zero pads); pre1 pads zeroed
__global__ void pre_init(const float* __restrict__ b1,
                         float* __restrict__ pre0, float* __restrict__ pre1)
{
    int t = blockIdx.x * blockDim.x + threadIdx.x;
    if (t >= NPL * AP) return;
    int c = t % AP;
    pre0[t] = (c < H2) ? fmaxf(b1[c], 0.f) : 0.f;
    if (c >= H2) pre1[t] = 0.f;
}

// ---------------------------------------------------------------------------
// Fused level step v3. 512 threads, TN=40 nodes/block, 250 blocks.
// Thread c<400 owns output col c=4o+g with its 50 weights in VGPRs.
//  stage: weights->VGPR/LDS, edge meta, xr
//  A: gather pre50 rows -> smA
//  B: p50 = relu(agg@WaT + deg*b2p + pb1) -> smP
//  C: Y[n][c] = b4i[c] + smP[n]·Wc + xs[n]·wx   (gi folded for r,z)
//  GRU: per (n,o): r=sig(Y1) z=sig(Y2) t=tanh(inn+r*Y3) h=(1-z)t+z*Y0 -> hs
//  D: pre50_out = relu(nb1 + hs@nwT)
//  E: coalesced state write
// ---------------------------------------------------------------------------
__global__ __launch_bounds__(512) void k3_kernel(
    const float* __restrict__ preIn, float* __restrict__ preOut,
    const int* __restrict__ fedge, int srcbase,
    const int* __restrict__ boffs, const int* __restrict__ bdeg,
    const int* __restrict__ bnbr,
    const float* __restrict__ xrL,
    const float* __restrict__ WaT, const float* __restrict__ b2p,
    const float* __restrict__ pb1,
    const float* __restrict__ W4i, const float* __restrict__ b4i,
    const float* __restrict__ wi, const float* __restrict__ bi,
    const float* __restrict__ nwT, const float* __restrict__ nb1,
    float* __restrict__ state_out)
{
    __shared__ float smA[TN * AP];     //  8.3 KB
    __shared__ float smP[TN * AP];     //  8.3 KB
    __shared__ float sWaT[H2 * AP];    // 10.4 KB
    __shared__ float sNwT[H2 * NWS];   // 21.6 KB
    __shared__ float Y[TN * YS];       // 64.6 KB
    __shared__ float hs[TN * HSS];     // 16.6 KB
    __shared__ float xs[TN * FD];
    __shared__ int sed[TN * KE];
    __shared__ int soff[TN];
    __shared__ int sdeg[TN];

    int tid = threadIdx.x;
    int nb = blockIdx.x * TN;
    int c = tid;                       // output col for phase C
    int g = c & 3, o4 = c >> 2;

    // ---- stage: per-thread weights (global, coalesced rows) ----
    float Wc[H2];
    float b4c = 0.f, wx0 = 0.f, wx1 = 0.f, wx2 = 0.f, wx3 = 0.f;
    if (c < 400) {
#pragma unroll
        for (int k = 0; k < H2; ++k) Wc[k] = W4i[k * 400 + c];
        b4c = b4i[c];
        if (g == 1 || g == 2) {
            int off = ((g == 1) ? o4 : (100 + o4)) * 4;
            wx0 = wi[off + 0]; wx1 = wi[off + 1]; wx2 = wi[off + 2]; wx3 = wi[off + 3];
        }
    }
    // LDS staging: WaT, nwT, xs, edge metadata
    for (int idx = tid; idx < H2 * AP / 4; idx += 512)
        ((float4*)sWaT)[idx] = ((const float4*)WaT)[idx];
    for (int idx = tid; idx < H2 * NWS / 4; idx += 512)
        ((float4*)sNwT)[idx] = ((const float4*)nwT)[idx];
    if (tid < TN)
        ((float4*)xs)[tid] = ((const float4*)xrL)[nb + tid];
    if (fedge) {
        if (tid < TN * KE) sed[tid] = fedge[nb * KE + tid] - srcbase;
    } else {
        if (tid < TN) { soff[tid] = boffs[nb + tid]; sdeg[tid] = bdeg[nb + tid]; }
    }
    __syncthreads();

    // ---- phase A: gather + sum pre50 rows -> smA ----
    const float4* pre4 = (const float4*)preIn;
    for (int idx = tid; idx < TN * 13; idx += 512) {
        int n = idx / 13, q = idx - n * 13;
        float4 a = make_float4(0.f, 0.f, 0.f, 0.f);
        if (fedge) {
#pragma unroll
            for (int e = 0; e < KE; ++e) {
                int r = sed[KE * n + e];
                float4 v = pre4[r * 13 + q];
                a.x += v.x; a.y += v.y; a.z += v.z; a.w += v.w;
            }
        } else {
            int off = soff[n], d = sdeg[n];
            for (int e = 0; e < d; ++e) {
                int r = bnbr[off + e];
                float4 v = pre4[r * 13 + q];
                a.x += v.x; a.y += v.y; a.z += v.z; a.w += v.w;
            }
        }
        *(float4*)&smA[n * AP + 4 * q] = a;
    }
    __syncthreads();

    // ---- phase B: p50 -> smP ----
    for (int idx = tid; idx < TN * H2; idx += 512) {
        int n = idx / H2, cc = idx - n * H2;
        float dgv = fedge ? 3.0f : (float)sdeg[n];
        float acc = pb1[cc] + dgv * b2p[cc];
        const float4* ar = (const float4*)&smA[n * AP];
        const float4* wr = (const float4*)&sWaT[cc * AP];
#pragma unroll
        for (int q = 0; q < 13; ++q) {
            float4 av = ar[q], wv = wr[q];
            acc = fmaf(av.x, wv.x, acc); acc = fmaf(av.y, wv.y, acc);
            acc = fmaf(av.z, wv.z, acc); acc = fmaf(av.w, wv.w, acc);
        }
        smP[n * AP + cc] = fmaxf(acc, 0.f);
    }
    __syncthreads();

    // ---- phase C: Y = b4 + P@W4i + xs@wx ----
    if (c < 400) {
#pragma unroll 2
        for (int n = 0; n < TN; ++n) {
            const float4* pr = (const float4*)&smP[n * AP];
            float acc = b4c;
#pragma unroll
            for (int q = 0; q < 13; ++q) {
                float4 pv = pr[q];
                acc = fmaf(pv.x, Wc[4 * q + 0], acc);
                acc = fmaf(pv.y, Wc[4 * q + 1], acc);
                acc = fmaf(pv.z, Wc[4 * q + 2], acc);
                acc = fmaf(pv.w, Wc[4 * q + 3], acc);
            }
            float4 xv = *(const float4*)&xs[n * FD];
            acc = fmaf(xv.x, wx0, acc); acc = fmaf(xv.y, wx1, acc);
            acc = fmaf(xv.z, wx2, acc); acc = fmaf(xv.w, wx3, acc);
            Y[n * YS + c] = acc;
        }
    }
    __syncthreads();

    // ---- GRU: per (n,o); o wave-uniform -> wi/bi via s_load ----
    {
        int w8 = __builtin_amdgcn_readfirstlane(tid >> 6);
        int n = tid & 63;
        if (n < TN) {
            float4 xv = *(const float4*)&xs[n * FD];
            for (int o = w8; o < H; o += 8) {
                float4 yv = *(const float4*)&Y[n * YS + 4 * o];
                float inn = bi[200 + o] + xv.x * wi[(200 + o) * 4 + 0]
                                        + xv.y * wi[(200 + o) * 4 + 1]
                                        + xv.z * wi[(200 + o) * 4 + 2]
                                        + xv.w * wi[(200 + o) * 4 + 3];
                float r = sigmoidf_(yv.y);
                float z = sigmoidf_(yv.z);
                float t = tanhf_(inn + r * yv.w);
                hs[n * HSS + o] = fmaf(z, yv.x - t, t);   // (1-z)t + z*m
            }
        }
    }
    __syncthreads();

    // ---- phase D: next step's pre50 ----
    for (int idx = tid; idx < TN * H2; idx += 512) {
        int n = idx / H2, cc = idx - n * H2;
        float acc = nb1[cc];
        const float4* hr = (const float4*)&hs[n * HSS];
        const float4* wr = (const float4*)&sNwT[cc * NWS];
#pragma unroll
        for (int q = 0; q < 25; ++q) {
            float4 hv = hr[q], wv = wr[q];
            acc = fmaf(hv.x, wv.x, acc); acc = fmaf(hv.y, wv.y, acc);
            acc = fmaf(hv.z, wv.z, acc); acc = fmaf(hv.w, wv.w, acc);
        }
        preOut[(size_t)(nb + n) * AP + cc] = fmaxf(acc, 0.f);
    }

    // ---- phase E: coalesced state write ----
    for (int idx = tid; idx < TN * H; idx += 512) {
        int n = idx / H, cc = idx - n * H;
        state_out[(size_t)(nb + n) * H + cc] = hs[n * HSS + cc];
    }
}

// ---------------------------------------------------------------------------
// xr = state @ proj_w + proj_b ; thread = (node, f)
// ---------------------------------------------------------------------------
__global__ __launch_bounds__(256) void proj_kernel(
    const float* __restrict__ state, const float* __restrict__ pw,
    const float* __restrict__ pb, float* __restrict__ xr)
{
    int t = blockIdx.x * 256 + threadIdx.x;
    if (t >= NT * FD) return;
    int node = t >> 2, f = t & 3;
    const float4* rp = (const float4*)(state + (size_t)node * H);
    float acc = pb[f];
    for (int i4 = 0; i4 < 25; ++i4) {
        float4 v = rp[i4];
        acc = fmaf(v.x, pw[(4 * i4 + 0) * 4 + f], acc);
        acc = fmaf(v.y, pw[(4 * i4 + 1) * 4 + f], acc);
        acc = fmaf(v.z, pw[(4 * i4 + 2) * 4 + f], acc);
        acc = fmaf(v.w, pw[(4 * i4 + 3) * 4 + f], acc);
    }
    xr[t] = acc;
}

// ---------------------------------------------------------------------------
__global__ void cls_kernel(const float* __restrict__ state,
                           const float* __restrict__ w1, const float* __restrict__ b1,
                           const float* __restrict__ w2, const float* __restrict__ b2,
                           float* __restrict__ pred)
{
    int n = blockIdx.x * blockDim.x + threadIdx.x;
    if (n >= NPL) return;
    float h[DM];
#pragma unroll
    for (int j = 0; j < DM; ++j) h[j] = b1[j];
    const float* sp = state + (size_t)n * H;
    for (int i = 0; i < H; ++i) {
        float s = sp[i];
#pragma unroll
        for (int j = 0; j < DM; ++j) h[j] = fmaf(s, w1[i * DM + j], h[j]);
    }
    float v = b2[0];
#pragma unroll
    for (int j = 0; j < DM; ++j) v = fmaf(fmaxf(h[j], 0.f), w2[j], v);
    pred[n] = sigmoidf_(v);
}

// ---------------------------------------------------------------------------
__global__ void gate_kernel(const float* __restrict__ x, const int* __restrict__ src,
                            float* __restrict__ pred, int l)
{
    int j = blockIdx.x * blockDim.x + threadIdx.x;
    if (j >= NPL) return;
    int e0 = (l - 1) * EPL + KE * j;
    int dg = l * NPL + j;
    float v0 = pred[src[e0 + 0]];
    float v1 = pred[src[e0 + 1]];
    float v2 = pred[src[e0 + 2]];
    const float invT = 100.0f;
    float mx = fmaxf(v0, fmaxf(v1, v2));
    float e0x = __expf((v0 - mx) * invT);
    float e1x = __expf((v1 - mx) * invT);
    float e2x = __expf((v2 - mx) * invT);
    float smax = (e0x * v0 + e1x * v1 + e2x * v2) / (e0x + e1x + e2x);
    float mn = fminf(v0, fminf(v1, v2));
    float f0 = __expf((mn - v0) * invT);
    float f1 = __expf((mn - v1) * invT);
    float f2 = __expf((mn - v2) * invT);
    float smin = (f0 * v0 + f1 * v1 + f2 * v2) / (f0 + f1 + f2);
    float am = x[(size_t)dg * FD + 1];
    float om = x[(size_t)dg * FD + 2];
    float nm = x[(size_t)dg * FD + 3];
    pred[dg] = am * smin + om * smax + nm * (3.f - (v0 + v1 + v2));
}

__global__ void copy_kernel(const float* __restrict__ pred, float* __restrict__ out)
{
    int j = blockIdx.x * blockDim.x + threadIdx.x;
    if (j < NPL) out[j] = pred[(NLV - 1) * NPL + j];
}

// ---------------------------------------------------------------------------
extern "C" void kernel_launch(void* const* d_in, const int* in_sizes, int n_in,
                              void* d_out, int out_size, void* d_ws, size_t ws_size,
                              hipStream_t stream)
{
    const float* x        = (const float*)d_in[0];
    const float* fpre_w1  = (const float*)d_in[1];
    const float* fpre_b1  = (const float*)d_in[2];
    const float* fpre_w2  = (const float*)d_in[3];
    const float* fpre_b2  = (const float*)d_in[4];
    const float* fpost_w1 = (const float*)d_in[5];
    const float* fpost_b1 = (const float*)d_in[6];
    const float* fpost_w2 = (const float*)d_in[7];
    const float* fpost_b2 = (const float*)d_in[8];
    const float* bpre_w1  = (const float*)d_in[9];
    const float* bpre_b1  = (const float*)d_in[10];
    const float* bpre_w2  = (const float*)d_in[11];
    const float* bpre_b2  = (const float*)d_in[12];
    const float* bpost_w1 = (const float*)d_in[13];
    const float* bpost_b1 = (const float*)d_in[14];
    const float* bpost_w2 = (const float*)d_in[15];
    const float* bpost_b2 = (const float*)d_in[16];
    const float* gruf_wi  = (const float*)d_in[17];
    const float* gruf_wh  = (const float*)d_in[18];
    const float* gruf_bi  = (const float*)d_in[19];
    const float* gruf_bh  = (const float*)d_in[20];
    const float* grub_wi  = (const float*)d_in[21];
    const float* grub_wh  = (const float*)d_in[22];
    const float* grub_bi  = (const float*)d_in[23];
    const float* grub_bh  = (const float*)d_in[24];
    const float* proj_w   = (const float*)d_in[25];
    const float* proj_b   = (const float*)d_in[26];
    const float* cls_w1   = (const float*)d_in[27];
    const float* cls_b1   = (const float*)d_in[28];
    const float* cls_w2   = (const float*)d_in[29];
    const float* cls_b2   = (const float*)d_in[30];
    const int*   src      = (const int*)d_in[31];
    const int*   dst      = (const int*)d_in[32];
    float* out = (float*)d_out;

    size_t o = 0;
    auto carve = [&](size_t nbytes) -> void* {
        void* p = (char*)d_ws + o;
        o += (nbytes + 255) & ~(size_t)255;
        return p;
    };
    float* state = (float*)carve((size_t)NT * H * 4);        // 48 MB
    float* xr    = (float*)carve((size_t)NT * FD * 4);
    float* pred  = (float*)carve((size_t)NT * 4);
    float* pre0  = (float*)carve((size_t)NPL * AP * 4);      // 2.08 MB
    float* pre1  = (float*)carve((size_t)NPL * AP * 4);
    int*   counts= (int*)carve((size_t)11 * NPL * 4);
    int*   cursor= (int*)carve((size_t)11 * NPL * 4);
    int*   offs  = (int*)carve((size_t)11 * NPL * 4);
    int*   nbrb  = (int*)carve((size_t)NE * 4);
    float* WaTF  = (float*)carve(H2 * AP * 4);
    float* b2pF  = (float*)carve(64 * 4);
    float* W4iF  = (float*)carve(H2 * 400 * 4);
    float* b4iF  = (float*)carve(400 * 4);
    float* nwTF  = (float*)carve(H2 * NWS * 4);
    float* WaTB  = (float*)carve(H2 * AP * 4);
    float* b2pB  = (float*)carve(64 * 4);
    float* W4iB  = (float*)carve(H2 * 400 * 4);
    float* b4iB  = (float*)carve(400 * 4);
    float* nwTB  = (float*)carve(H2 * NWS * 4);

    // zero counts AND cursor INCLUDING alignment padding between them
    hipMemsetAsync(counts, 0, (size_t)((char*)offs - (char*)counts), stream);

    fold_kernel<<<(2 * 28350 + 255) / 256, 256, 0, stream>>>(
        fpre_w2, fpre_b2, fpost_w1, fpost_w2, fpost_b2, gruf_wh, gruf_bh, gruf_bi, fpre_w1,
        bpre_w2, bpre_b2, bpost_w1, bpost_w2, bpost_b2, grub_wh, grub_bh, grub_bi, bpre_w1,
        WaTF, b2pF, W4iF, b4iF, nwTF,
        WaTB, b2pB, W4iB, b4iB, nwTB);
    csr_count<<<(NE + 255) / 256, 256, 0, stream>>>(src, counts);
    csr_scan<<<11, 256, 0, stream>>>(counts, offs);
    csr_fill<<<(NE + 255) / 256, 256, 0, stream>>>(src, dst, offs, cursor, nbrb);
    pre_init<<<(NPL * AP + 255) / 256, 256, 0, stream>>>(fpre_b1, pre0, pre1);

    float* preBuf[2] = { pre0, pre1 };
    int pb = 0;
    const int k3Grid = NPL / TN;   // 250

    for (int r = 0; r < 2; ++r) {
        const float* xr_use;
        if (r == 0) {
            xr_use = x;
        } else {
            proj_kernel<<<(NT * FD + 255) / 256, 256, 0, stream>>>(state, proj_w, proj_b, xr);
            xr_use = xr;
        }
        // forward levels 1..11
        for (int l = 1; l < NLV; ++l) {
            bool lastf = (l == NLV - 1);
            k3_kernel<<<k3Grid, 512, 0, stream>>>(
                preBuf[pb], preBuf[pb ^ 1],
                src + (size_t)(l - 1) * EPL, (l - 1) * NPL,
                nullptr, nullptr, nullptr,
                xr_use + (size_t)l * NPL * FD,
                WaTF, b2pF, fpost_b1, W4iF, b4iF, gruf_wi, gruf_bi,
                lastf ? nwTB : nwTF, lastf ? bpre_b1 : fpre_b1,
                state + (size_t)l * NPL * H);
            pb ^= 1;
        }
        // backward levels 10..0
        for (int f = NLV - 2; f >= 0; --f) {
            bool lastb = (f == 0);
            k3_kernel<<<k3Grid, 512, 0, stream>>>(
                preBuf[pb], preBuf[pb ^ 1],
                nullptr, 0,
                offs + (size_t)f * NPL, counts + (size_t)f * NPL, nbrb + (size_t)f * EPL,
                xr_use + (size_t)f * NPL * FD,
                WaTB, b2pB, bpost_b1, W4iB, b4iB, grub_wi, grub_bi,
                lastb ? nwTF : nwTB, lastb ? fpre_b1 : bpre_b1,
                state + (size_t)f * NPL * H);
            pb ^= 1;
        }
    }

    cls_kernel<<<(NPL + 255) / 256, 256, 0, stream>>>(state, cls_w1, cls_b1, cls_w2, cls_b2, pred);
    for (int l = 1; l < NLV; ++l)
        gate_kernel<<<(NPL + 255) / 256, 256, 0, stream>>>(x, src, pred, l);
    copy_kernel<<<(NPL + 255) / 256, 256, 0, stream>>>(pred, out);
}